// Round 1
// baseline (702.093 us; speedup 1.0000x reference)
//
#include <hip/hip_runtime.h>

#define B_ 16
#define C_ 80
#define H_ 128
#define W_ 128
#define HW_ (H_*W_)        // 16384
#define CHW_ (C_*HW_)      // 1310720
#define K_ 100
#define NCHUNK 32
#define CHUNK_ (CHW_/NCHUNK)   // 40960
#define THREADS 256
#define PER_THREAD (CHUNK_/THREADS) // 160
#define HIST_BITS 13
#define NBUCKET (1<<HIST_BITS)  // 8192
#define SEL_CAP 4096

static_assert(CHUNK_ * NCHUNK == CHW_, "chunking must tile exactly");

__device__ __forceinline__ bool is_local_max(const float* __restrict__ hb, int f, int y, int x, float v) {
    const bool xm = (x > 0), xp = (x < W_-1);
    if (xm && hb[f-1] > v) return false;
    if (xp && hb[f+1] > v) return false;
    if (y > 0) {
        const float* r = hb + (f - W_);
        if (r[0] > v) return false;
        if (xm && r[-1] > v) return false;
        if (xp && r[1] > v) return false;
    }
    if (y < H_-1) {
        const float* r = hb + (f + W_);
        if (r[0] > v) return false;
        if (xm && r[-1] > v) return false;
        if (xp && r[1] > v) return false;
    }
    return true;
}

// Per-chunk filtered top-K via LDS histogram radix-select + bitonic sort.
__global__ __launch_bounds__(THREADS)
void topk_chunk_kernel(const float* __restrict__ heat,
                       unsigned long long* __restrict__ chunkTop)
{
    __shared__ unsigned long long sel[SEL_CAP];   // 32 KB (overlaid by hist in phase 1)
    __shared__ unsigned int seg[THREADS];
    __shared__ unsigned int s_cnt;
    __shared__ unsigned int s_pivot;
    unsigned int* hist = (unsigned int*)sel;      // 8192 u32 == 32 KB overlay

    const int tid = threadIdx.x;
    const int chunk = blockIdx.x;
    const int b = blockIdx.y;
    const float* hb = heat + (size_t)b * CHW_;
    const int f0 = chunk * CHUNK_;

    for (int i = tid; i < NBUCKET; i += THREADS) hist[i] = 0;
    if (tid == 0) s_cnt = 0;
    __syncthreads();

    // Phase 1: histogram of float-bit keys of local-max survivors
    for (int it = 0; it < PER_THREAD; ++it) {
        const int f = f0 + it*THREADS + tid;
        const float v = hb[f];
        if (!(v > 0.0f)) continue;
        const int r = f & (HW_-1);
        const int y = r >> 7, x = r & (W_-1);
        if (is_local_max(hb, f, y, x, v))
            atomicAdd(&hist[__float_as_uint(v) >> (32-HIST_BITS)], 1u);
    }
    __syncthreads();

    // Segment sums (descending segments of 32 buckets each)
    {
        unsigned int s = 0;
        const int hi = NBUCKET - tid*32;
        for (int i = hi-32; i < hi; ++i) s += hist[i];
        seg[tid] = s;
    }
    __syncthreads();

    if (tid == 0) {
        unsigned int cum = 0, p = 0; bool found = false;
        for (int t = 0; t < THREADS && !found; ++t) {
            const unsigned int s = seg[t];
            if (cum + s >= (unsigned)K_) {
                const int hi = NBUCKET - t*32;
                for (int i = hi-1; i >= hi-32; --i) {
                    cum += hist[i];
                    if (cum >= (unsigned)K_) { p = (unsigned)i; found = true; break; }
                }
            } else {
                cum += s;
            }
        }
        s_pivot = found ? p : 0u;
    }
    __syncthreads();
    const unsigned int pivotBits = s_pivot << (32-HIST_BITS);
    // (hist region is dead from here; sel reuses it)

    // Phase 2: collect candidates >= pivot bucket
    for (int it = 0; it < PER_THREAD; ++it) {
        const int f = f0 + it*THREADS + tid;
        const float v = hb[f];
        if (!(v > 0.0f)) continue;
        const unsigned int bits = __float_as_uint(v);
        if (bits < pivotBits) continue;
        const int r = f & (HW_-1);
        const int y = r >> 7, x = r & (W_-1);
        if (!is_local_max(hb, f, y, x, v)) continue;
        const unsigned int pos = atomicAdd(&s_cnt, 1u);
        if (pos < SEL_CAP) {
            // key: value-descending, index-ascending; store complemented for ascending sort
            const unsigned long long key =
                ((unsigned long long)bits << 32) | (unsigned int)(f ^ 0xFFFFFFFFu);
            sel[pos] = ~key;
        }
    }
    __syncthreads();

    int M = (int)s_cnt; if (M > SEL_CAP) M = SEL_CAP;
    int n = 128; while (n < M) n <<= 1;   // n in [128, 4096]
    for (int i = M + tid; i < n; i += THREADS) sel[i] = ~0ULL;

    // Bitonic sort ascending (complemented keys -> value-descending)
    for (int k = 2; k <= n; k <<= 1)
        for (int j = k >> 1; j > 0; j >>= 1) {
            __syncthreads();
            for (int i = tid; i < n; i += THREADS) {
                const int ixj = i ^ j;
                if (ixj > i) {
                    const unsigned long long a = sel[i], bb = sel[ixj];
                    const bool asc = ((i & k) == 0);
                    if ((a > bb) == asc) { sel[i] = bb; sel[ixj] = a; }
                }
            }
        }
    __syncthreads();

    unsigned long long* op = chunkTop + (size_t)(b*NCHUNK + chunk) * K_;
    for (int i = tid; i < K_; i += THREADS) op[i] = sel[i];
}

// Merge per-chunk top-K per batch, decode bboxes + labels.
__global__ __launch_bounds__(THREADS)
void merge_decode_kernel(const unsigned long long* __restrict__ chunkTop,
                         const float* __restrict__ wh,
                         const float* __restrict__ off,
                         float* __restrict__ out)
{
    __shared__ unsigned long long arr[4096];
    const int tid = threadIdx.x;
    const int b = blockIdx.x;
    const int NC = NCHUNK * K_;   // 3200

    const unsigned long long* src = chunkTop + (size_t)b * NC;
    for (int i = tid; i < NC; i += THREADS) arr[i] = src[i];
    for (int i = NC + tid; i < 4096; i += THREADS) arr[i] = ~0ULL;
    __syncthreads();

    const int n = 4096;
    for (int k = 2; k <= n; k <<= 1)
        for (int j = k >> 1; j > 0; j >>= 1) {
            __syncthreads();
            for (int i = tid; i < n; i += THREADS) {
                const int ixj = i ^ j;
                if (ixj > i) {
                    const unsigned long long a = arr[i], bb = arr[ixj];
                    const bool asc = ((i & k) == 0);
                    if ((a > bb) == asc) { arr[i] = bb; arr[ixj] = a; }
                }
            }
        }
    __syncthreads();

    if (tid < K_) {
        const unsigned long long key = ~arr[tid];
        const unsigned int bits = (unsigned int)(key >> 32);
        const unsigned int f = (unsigned int)(key & 0xFFFFFFFFu) ^ 0xFFFFFFFFu;
        const float score = __uint_as_float(bits);
        const int label = (int)(f / HW_);
        const int r = (int)(f & (HW_-1));
        const int y = r >> 7, x = r & (W_-1);

        const float* whb = wh  + (size_t)b * 2 * HW_;
        const float* ofb = off + (size_t)b * 2 * HW_;
        const float w0 = whb[r], w1 = whb[HW_ + r];
        const float o0 = ofb[r], o1 = ofb[HW_ + r];

        const float xs = (float)x + o0;
        const float ys = (float)y + o1;
        const float hw = w0 * 0.5f, hh = w1 * 0.5f;
        const float sx = 4.0f, sy = 4.0f;   // 512/128

        float* ob = out + ((size_t)b * K_ + tid) * 5;
        ob[0] = (xs - hw) * sx;
        ob[1] = (ys - hh) * sy;
        ob[2] = (xs + hw) * sx;
        ob[3] = (ys + hh) * sy;
        ob[4] = score;

        out[(size_t)B_ * K_ * 5 + b * K_ + tid] = (float)label;
    }
}

extern "C" void kernel_launch(void* const* d_in, const int* in_sizes, int n_in,
                              void* d_out, int out_size, void* d_ws, size_t ws_size,
                              hipStream_t stream) {
    const float* heat = (const float*)d_in[0];
    const float* wh   = (const float*)d_in[1];
    const float* off  = (const float*)d_in[2];
    float* out = (float*)d_out;
    unsigned long long* chunkTop = (unsigned long long*)d_ws; // 512*100*8 = 409600 B

    dim3 gA(NCHUNK, B_);
    topk_chunk_kernel<<<gA, THREADS, 0, stream>>>(heat, chunkTop);
    merge_decode_kernel<<<B_, THREADS, 0, stream>>>(chunkTop, wh, off, out);
}

// Round 2
// 96.171 us; speedup vs baseline: 7.3005x; 7.3005x over previous
//
#include <hip/hip_runtime.h>

typedef unsigned long long u64;
typedef unsigned int u32;

#define B_ 16
#define C_ 80
#define H_ 128
#define W_ 128
#define HW_ (H_*W_)        // 16384
#define K_ 100
#define LIST_CAP 3072
#define OUT_CAP 128
#define NB1 4096

// ---------------- Kernel A: per-(b,c) plane local-max + exact top-K-superset select ----------------

// push survivor keys into LDS list via wave-ballot compaction
#define PUSH(sv, val, fb) do {                                                         \
    unsigned long long m_ = __ballot(sv);                                              \
    if (m_) {                                                                          \
        u32 base_ = 0;                                                                 \
        if (lane == 0) base_ = atomicAdd(&s_cnt, (u32)__popcll(m_));                   \
        base_ = (u32)__shfl((int)base_, 0);                                            \
        if (sv) {                                                                      \
            u32 pos_ = base_ + (u32)__popcll(m_ & ((1ull << lane) - 1));               \
            if (pos_ < LIST_CAP)                                                       \
                list[pos_] = ((u64)__float_as_uint(val) << 32) | (u32)(~(u32)(fb));    \
        }                                                                              \
    }                                                                                  \
} while (0)

// radix-select pivot over 4096-bucket hist: finds s_p (pivot bucket) and s_above
// (count in buckets strictly above pivot) for threshold Kneed. Needs barrier-clean hist.
#define SUFFIX_SELECT(Kneed) do {                                                      \
    u32 ssum_ = 0; int b16_ = tid << 4;                                                \
    for (int i_ = 0; i_ < 16; ++i_) ssum_ += hist[b16_ + i_];                          \
    seg[tid] = ssum_; __syncthreads();                                                 \
    for (int d_ = 1; d_ < 256; d_ <<= 1) {                                             \
        u32 v_ = (tid + d_ < 256) ? seg[tid + d_] : 0;                                 \
        __syncthreads(); seg[tid] += v_; __syncthreads();                              \
    }                                                                                  \
    if (tid == 0) { s_ps = 0; s_aseg = 0; } __syncthreads();                           \
    { u32 sufme_ = seg[tid]; u32 sufnx_ = (tid < 255) ? seg[tid + 1] : 0;              \
      if (sufme_ >= (Kneed) && (tid == 255 || sufnx_ < (Kneed))) {                     \
          s_ps = tid; s_aseg = sufnx_; } }                                             \
    __syncthreads();                                                                   \
    if (tid == 0) {                                                                    \
        u32 cum_ = s_aseg; int ps_ = s_ps;                                             \
        u32 piv_ = (u32)(ps_ << 4); u32 abv_ = cum_;                                   \
        for (int i_ = 15; i_ >= 0; --i_) {                                             \
            u32 h_ = hist[(ps_ << 4) + i_];                                            \
            if (cum_ + h_ >= (Kneed)) { piv_ = (u32)((ps_ << 4) + i_); abv_ = cum_; break; } \
            cum_ += h_;                                                                \
        }                                                                              \
        s_p = piv_; s_above = abv_;                                                    \
    }                                                                                  \
    __syncthreads();                                                                   \
} while (0)

__global__ __launch_bounds__(256)
void select_kernel(const float* __restrict__ heat, u64* __restrict__ chanOut)
{
    __shared__ u64 list[LIST_CAP];     // 24 KB
    __shared__ u32 hist[NB1];          // 16 KB
    __shared__ u32 seg[256];
    __shared__ u64 out2[OUT_CAP];
    __shared__ u32 s_cnt, s_cnt2, s_ps, s_aseg, s_p, s_above;

    const int tid = threadIdx.x;
    const int lane = tid & 63;
    const int c = blockIdx.x, b = blockIdx.y;
    const float* hb = heat + ((size_t)(b * C_ + c) << 14);

    for (int i = tid; i < NB1; i += 256) hist[i] = 0;
    for (int i = tid; i < OUT_CAP; i += 256) out2[i] = 0ull;
    if (tid == 0) { s_cnt = 0; s_cnt2 = 0; }
    __syncthreads();

    const int rl = tid >> 5;            // 0..7 row within 8-row band
    const int c4 = (tid & 31) << 2;     // col group 0,4,...,124
    const bool colL = (c4 == 0), colR = (c4 == 124);
    const float NEG = -__builtin_huge_valf();

    for (int it = 0; it < 16; ++it) {
        const int r = (it << 3) + rl;
        const int rm = (r > 0) ? r - 1 : 0;
        const int rp = (r < H_-1) ? r + 1 : H_-1;
        const float4 a  = *(const float4*)(hb + (rm << 7) + c4);
        const float4 bq = *(const float4*)(hb + (r  << 7) + c4);
        const float4 cq = *(const float4*)(hb + (rp << 7) + c4);
        const float v0 = fmaxf(fmaxf(a.x, bq.x), cq.x);
        const float v1 = fmaxf(fmaxf(a.y, bq.y), cq.y);
        const float v2 = fmaxf(fmaxf(a.z, bq.z), cq.z);
        const float v3 = fmaxf(fmaxf(a.w, bq.w), cq.w);
        float left  = __shfl_up(v3, 1);
        float right = __shfl_down(v0, 1);
        if (colL) left = NEG;
        if (colR) right = NEG;
        const float h0 = fmaxf(left, fmaxf(v0, v1));
        const float h1 = fmaxf(v0, fmaxf(v1, v2));
        const float h2 = fmaxf(v1, fmaxf(v2, v3));
        const float h3 = fmaxf(v2, fmaxf(v3, right));
        const int fb = (c << 14) | (r << 7) | c4;
        const bool s0 = (h0 == bq.x), s1 = (h1 == bq.y), s2 = (h2 == bq.z), s3 = (h3 == bq.w);
        PUSH(s0, bq.x, fb + 0);
        PUSH(s1, bq.y, fb + 1);
        PUSH(s2, bq.z, fb + 2);
        PUSH(s3, bq.w, fb + 3);
    }
    __syncthreads();

    const u32 cnt = min(s_cnt, (u32)LIST_CAP);

    // level-1 histogram on bits>>20 (key>>52)
    for (u32 i = tid; i < cnt; i += 256) atomicAdd(&hist[(u32)(list[i] >> 52)], 1u);
    __syncthreads();

    SUFFIX_SELECT((u32)K_);
    const u32 P1 = s_p, G1 = s_above;
    const u32 C1 = G1 + hist[P1];
    const bool refine = (C1 > (u32)OUT_CAP);
    u32 P2 = 0;

    if (refine) {
        for (int i = tid; i < NB1; i += 256) hist[i] = 0;
        __syncthreads();
        for (u32 i = tid; i < cnt; i += 256) {
            const u64 key = list[i];
            if ((u32)(key >> 52) == P1)
                atomicAdd(&hist[(u32)(key >> 40) & 0xFFFu], 1u);
        }
        __syncthreads();
        SUFFIX_SELECT((u32)K_ - G1);
        P2 = s_p;
    }

    // final compaction
    for (u32 i = tid; i < cnt; i += 256) {
        const u64 key = list[i];
        const u32 bk = (u32)(key >> 52);
        bool sel;
        if (refine) sel = (bk > P1) || (bk == P1 && ((u32)(key >> 40) & 0xFFFu) >= P2);
        else        sel = (bk >= P1);
        if (sel) {
            const u32 pos = atomicAdd(&s_cnt2, 1u);
            if (pos < (u32)OUT_CAP) out2[pos] = key;
        }
    }
    __syncthreads();

    u64* op = chanOut + ((size_t)(b * C_ + c) << 7);
    for (int i = tid; i < OUT_CAP; i += 256) op[i] = out2[i];
}

// ---------------- Kernel B1: merge 8 channels (1024 keys) -> sorted top-100 ----------------
__global__ __launch_bounds__(512)
void merge8_kernel(const u64* __restrict__ chanOut, u64* __restrict__ grpOut)
{
    __shared__ u64 arr[1024];
    const int tid = threadIdx.x;
    const int g = blockIdx.x, b = blockIdx.y;
    const u64* src = chanOut + (size_t)(b * C_ + g * 8) * OUT_CAP;
    arr[tid] = src[tid];
    arr[tid + 512] = src[tid + 512];
    __syncthreads();

    for (int k = 2; k <= 1024; k <<= 1)
        for (int j = k >> 1; j > 0; j >>= 1) {
            __syncthreads();
            for (int i = tid; i < 1024; i += 512) {
                const int ixj = i ^ j;
                if (ixj > i) {
                    const u64 a = arr[i], bb = arr[ixj];
                    const bool asc = ((i & k) == 0);
                    if ((a < bb) == asc) { arr[i] = bb; arr[ixj] = a; }  // descending
                }
            }
        }
    __syncthreads();

    if (tid < K_) grpOut[(size_t)(b * 10 + g) * K_ + tid] = arr[tid];
}

// ---------------- Kernel B2: merge 10 groups (1000 keys) -> final top-100 + decode ----------------
__global__ __launch_bounds__(512)
void final_kernel(const u64* __restrict__ grpOut,
                  const float* __restrict__ wh,
                  const float* __restrict__ off,
                  float* __restrict__ out)
{
    __shared__ u64 arr[1024];
    const int tid = threadIdx.x;
    const int b = blockIdx.x;
    const u64* src = grpOut + (size_t)b * (10 * K_);
    arr[tid]       = (tid < 1000) ? src[tid] : 0ull;
    arr[tid + 512] = (tid + 512 < 1000) ? src[tid + 512] : 0ull;
    __syncthreads();

    for (int k = 2; k <= 1024; k <<= 1)
        for (int j = k >> 1; j > 0; j >>= 1) {
            __syncthreads();
            for (int i = tid; i < 1024; i += 512) {
                const int ixj = i ^ j;
                if (ixj > i) {
                    const u64 a = arr[i], bb = arr[ixj];
                    const bool asc = ((i & k) == 0);
                    if ((a < bb) == asc) { arr[i] = bb; arr[ixj] = a; }
                }
            }
        }
    __syncthreads();

    if (tid < K_) {
        const u64 key = arr[tid];
        const u32 bits = (u32)(key >> 32);
        const u32 f = ~(u32)key;
        const float score = __uint_as_float(bits);
        const int label = (int)(f >> 14);
        const int r = (int)(f & (HW_ - 1));
        const int y = r >> 7, x = r & (W_ - 1);

        const float* whb = wh  + (size_t)b * 2 * HW_;
        const float* ofb = off + (size_t)b * 2 * HW_;
        const float w0 = whb[r], w1 = whb[HW_ + r];
        const float o0 = ofb[r], o1 = ofb[HW_ + r];

        const float xs = (float)x + o0;
        const float ys = (float)y + o1;
        const float hw = w0 * 0.5f, hh = w1 * 0.5f;
        const float sx = 4.0f, sy = 4.0f;   // 512/128

        float* ob = out + ((size_t)b * K_ + tid) * 5;
        ob[0] = (xs - hw) * sx;
        ob[1] = (ys - hh) * sy;
        ob[2] = (xs + hw) * sx;
        ob[3] = (ys + hh) * sy;
        ob[4] = score;

        out[(size_t)B_ * K_ * 5 + b * K_ + tid] = (float)label;
    }
}

extern "C" void kernel_launch(void* const* d_in, const int* in_sizes, int n_in,
                              void* d_out, int out_size, void* d_ws, size_t ws_size,
                              hipStream_t stream) {
    const float* heat = (const float*)d_in[0];
    const float* wh   = (const float*)d_in[1];
    const float* off  = (const float*)d_in[2];
    float* out = (float*)d_out;

    u64* chanOut = (u64*)d_ws;                                   // 16*80*128*8 = 1,310,720 B
    u64* grpOut  = (u64*)((char*)d_ws + (size_t)B_ * C_ * OUT_CAP * 8);  // 16*10*100*8 = 128,000 B

    dim3 gA(C_, B_);
    select_kernel<<<gA, 256, 0, stream>>>(heat, chanOut);
    dim3 gB1(10, B_);
    merge8_kernel<<<gB1, 512, 0, stream>>>(chanOut, grpOut);
    final_kernel<<<B_, 512, 0, stream>>>(grpOut, wh, off, out);
}